// Round 3
// baseline (274.146 us; speedup 1.0000x reference)
//
#include <hip/hip_runtime.h>
#include <hip/hip_bf16.h>

typedef __hip_bfloat16 bf16;
typedef __attribute__((ext_vector_type(8))) short bf16x8;   // 8 bf16 = 4 VGPRs
typedef __attribute__((ext_vector_type(4))) float f32x4;
typedef __attribute__((ext_vector_type(16))) float f32x16;

static constexpr int SEQ = 2048;   // sequence length
static constexpr int HDIM = 1024;  // H*D
static constexpr int NH = 16;      // heads
static constexpr int DH = 64;      // per-head dim

__device__ __forceinline__ f32x4 mfma16(bf16x8 a, bf16x8 b, f32x4 c) {
  return __builtin_amdgcn_mfma_f32_16x16x32_bf16(a, b, c, 0, 0, 0);
}
__device__ __forceinline__ f32x16 mfma32(bf16x8 a, bf16x8 b, f32x16 c) {
  return __builtin_amdgcn_mfma_f32_32x32x16_bf16(a, b, c, 0, 0, 0);
}

// async global->LDS, 16B per lane; LDS dest must be wave-uniform base (lane*16 implicit)
__device__ __forceinline__ void gload_lds16(const bf16* g, bf16* l) {
  __builtin_amdgcn_global_load_lds(
      (const __attribute__((address_space(1))) void*)g,
      (__attribute__((address_space(3))) void*)l, 16, 0, 0);
}

__device__ __forceinline__ unsigned packbf(float a, float b) {
  unsigned short ua = __builtin_bit_cast(unsigned short, __float2bfloat16(a));
  unsigned short ub = __builtin_bit_cast(unsigned short, __float2bfloat16(b));
  return (unsigned)ua | ((unsigned)ub << 16);
}

// ---------------- fp32 -> bf16 convert (vectorized) ----------------
__global__ __launch_bounds__(256) void cvt_bf16(const float* __restrict__ in,
                                                bf16* __restrict__ out, int n4) {
  int i = blockIdx.x * blockDim.x + threadIdx.x;
  if (i >= n4) return;
  float4 v = reinterpret_cast<const float4*>(in)[i];
  bf16 t[4] = {__float2bfloat16(v.x), __float2bfloat16(v.y),
               __float2bfloat16(v.z), __float2bfloat16(v.w)};
  reinterpret_cast<ushort4*>(out)[i] = *reinterpret_cast<ushort4*>(t);
}

// ---------------- GEMM core: C[128x128] += A[128xK] * W[128xK]^T ----------------
__device__ __forceinline__ void gemm_core(const bf16* __restrict__ A,
                                          const bf16* __restrict__ W,
                                          int m0, int n0, int K,
                                          f32x4 (&acc)[4][4],
                                          bf16* As, bf16* Bs) {
  const int tid = threadIdx.x;
  const int w = tid >> 6, lane = tid & 63;
  const int wr = w >> 1, wc = w & 1;
  const int lr = lane & 15, lk = (lane >> 4) * 8;
  const int srow = lane >> 2, scol = (lane & 3) * 8;

  for (int kt = 0; kt < K; kt += 32) {
#pragma unroll
    for (int j = 0; j < 2; ++j) {
      int cidx = w * 2 + j;
      int r = cidx * 16 + srow;
      gload_lds16(A + (size_t)(m0 + r) * K + kt + scol, As + cidx * 512);
      gload_lds16(W + (size_t)(n0 + r) * K + kt + scol, Bs + cidx * 512);
    }
    __syncthreads();
    bf16x8 af[4], bw[4];
#pragma unroll
    for (int i = 0; i < 4; ++i)
      af[i] = *reinterpret_cast<const bf16x8*>(As + (wr * 64 + i * 16 + lr) * 32 + lk);
#pragma unroll
    for (int i = 0; i < 4; ++i)
      bw[i] = *reinterpret_cast<const bf16x8*>(Bs + (wc * 64 + i * 16 + lr) * 32 + lk);
#pragma unroll
    for (int r = 0; r < 4; ++r)
#pragma unroll
      for (int c = 0; c < 4; ++c)
        acc[r][c] = mfma16(af[r], bw[c], acc[r][c]);
    __syncthreads();
  }
}

// ---------------- fused QKV projection ----------------
// z=0: Q -> [B,H,S,D], pre-scaled by (1/sqrt(D))*log2(e) so softmax is exp2-domain
__global__ __launch_bounds__(256)
void qkv_gemm(const bf16* __restrict__ xb,
              const bf16* __restrict__ wq, const bf16* __restrict__ wk,
              const bf16* __restrict__ wv,
              const float* __restrict__ bq, const float* __restrict__ bk,
              const float* __restrict__ bv,
              bf16* __restrict__ qd, bf16* __restrict__ kd, bf16* __restrict__ vT) {
  __shared__ bf16 As[128 * 32], Bs[128 * 32];
  const int z = blockIdx.z;
  const bf16* W = (z == 0) ? wq : (z == 1) ? wk : wv;
  const float* bias = (z == 0) ? bq : (z == 1) ? bk : bv;
  const float scale = (z == 0) ? 0.18033688011f : 1.0f;  // 0.125 * log2(e)
  const int m0 = blockIdx.y * 128, n0 = blockIdx.x * 128;
  f32x4 acc[4][4] = {};
  gemm_core(xb, W, m0, n0, HDIM, acc, As, Bs);

  const int tid = threadIdx.x, w = tid >> 6, lane = tid & 63;
  const int wr = w >> 1, wc = w & 1;
  const int lr = lane & 15, rg = (lane >> 4) * 4;
#pragma unroll
  for (int r = 0; r < 4; ++r)
#pragma unroll
    for (int c = 0; c < 4; ++c) {
      int n = n0 + wc * 64 + c * 16 + lr;
      int h = n >> 6, d = n & 63;
      float bz = bias[n];
#pragma unroll
      for (int q = 0; q < 4; ++q) {
        int m = m0 + wr * 64 + r * 16 + rg + q;
        int b = m >> 11, s = m & 2047;
        bf16 val = __float2bfloat16((acc[r][c][q] + bz) * scale);
        if (z == 2)
          vT[(((size_t)(b * NH + h) * DH + d) << 11) + s] = val;
        else {
          bf16* dst = (z == 0) ? qd : kd;
          dst[(((size_t)(b * NH + h) * SEQ + s) << 6) + d] = val;
        }
      }
    }
}

// ---------------- flash attention, swapped QK^T + in-block split-K ----------------
// grid (S/128, B*H), 512 threads = 8 waves.
// wave wv: qw = wv&3 selects 32 q-rows; kh = wv>>2 selects k-half (1024 rows).
// Partials merged through LDS in the epilogue.
__global__ __launch_bounds__(512, 4)
void attn_kernel(const bf16* __restrict__ Q, const bf16* __restrict__ K,
                 const bf16* __restrict__ vT, bf16* __restrict__ AO) {
  __shared__ float Olds[4][32][64];           // kh=1 partial O
  __shared__ float mlds[4][32], llds[4][32];  // kh=1 partial m, l
  __shared__ float als[8][32];                // per-wave alpha / scale broadcast
  __shared__ float af1[4][32], af2[4][32], li[4][32];

  const int lane = threadIdx.x & 63;
  const int wv = threadIdx.x >> 6;
  const int qw = wv & 3, kh = wv >> 2;
  const int l31 = lane & 31;
  const int hi = lane >> 5;
  const int bh = blockIdx.y;
  const int b = bh >> 4, h = bh & 15;
  const int q0 = blockIdx.x * 128 + qw * 32;

  const bf16* Qh = Q + (size_t)bh * SEQ * DH;
  const bf16* Kh = K + (size_t)bh * SEQ * DH;
  const bf16* Vh = vT + (size_t)bh * DH * SEQ;

  // Q B-frags hoisted: col=q=l31, k-elems d = step*16 + hi*8 + i
  bf16x8 qf[4];
#pragma unroll
  for (int s = 0; s < 4; ++s)
    qf[s] = *reinterpret_cast<const bf16x8*>(
        Qh + (size_t)(q0 + l31) * DH + s * 16 + hi * 8);

  f32x16 o0 = {}, o1 = {};           // O[q-set][d], d = {0..31, 32..63}
  float m = -1e30f, l = 0.f;         // log2-domain softmax state for q = l31

  const int k_lo = kh << 10, k_hi = k_lo + 1024;
  for (int kt = k_lo; kt < k_hi; kt += 32) {
    // QK^T swapped: A = K (row=k, contiguous d), B = Q (col=q)
    f32x16 sacc = {};
#pragma unroll
    for (int s = 0; s < 4; ++s) {
      bf16x8 kf = *reinterpret_cast<const bf16x8*>(
          Kh + (size_t)(kt + l31) * DH + s * 16 + hi * 8);
      sacc = mfma32(kf, qf[s], sacc);
    }
    // V B-frags: col=d (within tile), k contiguous from vT[d][k]
    bf16x8 vf[2][2];
#pragma unroll
    for (int kk = 0; kk < 2; ++kk)
#pragma unroll
      for (int t = 0; t < 2; ++t)
        vf[kk][t] = *reinterpret_cast<const bf16x8*>(
            Vh + (size_t)(t * 32 + l31) * SEQ + kt + kk * 16 + hi * 8);

    // row max: depth-4 tree + 1 cross-half shfl
    float tm[8];
#pragma unroll
    for (int i = 0; i < 8; ++i) tm[i] = fmaxf(sacc[2 * i], sacc[2 * i + 1]);
#pragma unroll
    for (int i = 0; i < 4; ++i) tm[i] = fmaxf(tm[i], tm[i + 4]);
    float pmax = fmaxf(fmaxf(tm[0], tm[1]), fmaxf(tm[2], tm[3]));
    pmax = fmaxf(pmax, __shfl_xor(pmax, 32));

    if (__any(pmax > m + 11.5415603f)) {  // defer-max (8 nats in log2 units)
      float mn = fmaxf(m, pmax);
      float al = exp2f(m - mn);           // first tile: exp2(-inf) = 0
      m = mn; l *= al;
      if (lane < 32) als[wv][l31] = al;
      __builtin_amdgcn_wave_barrier();
#pragma unroll
      for (int r = 0; r < 16; ++r) {
        float a = als[wv][(r & 3) + 8 * (r >> 2) + 4 * hi];
        o0[r] *= a; o1[r] *= a;
      }
      __builtin_amdgcn_wave_barrier();
    }

    float p[16];
#pragma unroll
    for (int i = 0; i < 16; ++i) p[i] = exp2f(sacc[i] - m);
    // sum: depth-4 tree + 1 shfl
    float ts[8];
#pragma unroll
    for (int i = 0; i < 8; ++i) ts[i] = p[2 * i] + p[2 * i + 1];
#pragma unroll
    for (int i = 0; i < 4; ++i) ts[i] = ts[i] + ts[i + 4];
    float ps = (ts[0] + ts[1]) + (ts[2] + ts[3]);
    ps += __shfl_xor(ps, 32);
    l += ps;

    // pack P to bf16 pairs; one cross-half exchange builds PV A-frags.
    unsigned w[4][2], sw[4][2];
#pragma unroll
    for (int g = 0; g < 4; ++g) {
      w[g][0] = packbf(p[4 * g + 0], p[4 * g + 1]);
      w[g][1] = packbf(p[4 * g + 2], p[4 * g + 3]);
      sw[g][0] = __shfl_xor(w[g][0], 32);
      sw[g][1] = __shfl_xor(w[g][1], 32);
    }
#pragma unroll
    for (int kk = 0; kk < 2; ++kk) {
      union { unsigned u[4]; bf16x8 v; } fa;
      fa.u[0] = hi ? sw[2 * kk + 1][0] : w[2 * kk][0];
      fa.u[1] = hi ? sw[2 * kk + 1][1] : w[2 * kk][1];
      fa.u[2] = hi ? w[2 * kk + 1][0] : sw[2 * kk][0];
      fa.u[3] = hi ? w[2 * kk + 1][1] : sw[2 * kk][1];
      o0 = mfma32(fa.v, vf[kk][0], o0);
      o1 = mfma32(fa.v, vf[kk][1], o1);
    }
  }

  // ---- merge the two k-halves through LDS ----
  if (kh == 1) {
    if (lane < 32) { mlds[qw][l31] = m; llds[qw][l31] = l; }
#pragma unroll
    for (int r = 0; r < 16; ++r) {
      int q = (r & 3) + 8 * (r >> 2) + 4 * hi;
      Olds[qw][q][l31] = o0[r];
      Olds[qw][q][32 + l31] = o1[r];
    }
  }
  __syncthreads();
  if (kh == 0) {
    float m2 = mlds[qw][l31], l2 = llds[qw][l31];
    float mn = fmaxf(m, m2);
    float a1 = exp2f(m - mn), a2 = exp2f(m2 - mn);
    float inv = 1.0f / (l * a1 + l2 * a2);
    if (lane < 32) { af1[qw][l31] = a1; af2[qw][l31] = a2; li[qw][l31] = inv; }
    __builtin_amdgcn_wave_barrier();
#pragma unroll
    for (int r = 0; r < 16; ++r) {
      int q = (r & 3) + 8 * (r >> 2) + 4 * hi;
      float s1 = af1[qw][q], s2 = af2[qw][q], iv = li[qw][q];
      size_t row = (size_t)(b * SEQ + q0 + q) * HDIM + h * DH;
      AO[row + l31] =
          __float2bfloat16((o0[r] * s1 + Olds[qw][q][l31] * s2) * iv);
      AO[row + 32 + l31] =
          __float2bfloat16((o1[r] * s1 + Olds[qw][q][32 + l31] * s2) * iv);
    }
  }
}

// ---------------- final projection: fp32 out ----------------
__global__ __launch_bounds__(256)
void fc_gemm(const bf16* __restrict__ A, const bf16* __restrict__ W,
             const float* __restrict__ bias, float* __restrict__ out) {
  __shared__ bf16 As[128 * 32], Bs[128 * 32];
  const int m0 = blockIdx.y * 128, n0 = blockIdx.x * 128;
  f32x4 acc[4][4] = {};
  gemm_core(A, W, m0, n0, HDIM, acc, As, Bs);

  const int tid = threadIdx.x, w = tid >> 6, lane = tid & 63;
  const int wr = w >> 1, wc = w & 1;
  const int lr = lane & 15, rg = (lane >> 4) * 4;
#pragma unroll
  for (int r = 0; r < 4; ++r)
#pragma unroll
    for (int c = 0; c < 4; ++c) {
      int n = n0 + wc * 64 + c * 16 + lr;
      float bz = bias[n];
#pragma unroll
      for (int q = 0; q < 4; ++q) {
        int m = m0 + wr * 64 + r * 16 + rg + q;
        out[(size_t)m * HDIM + n] = acc[r][c][q] + bz;
      }
    }
}

extern "C" void kernel_launch(void* const* d_in, const int* in_sizes, int n_in,
                              void* d_out, int out_size, void* d_ws, size_t ws_size,
                              hipStream_t stream) {
  (void)in_sizes; (void)n_in; (void)out_size; (void)ws_size;
  const float* x  = (const float*)d_in[0];
  const float* wq = (const float*)d_in[1];
  const float* bq = (const float*)d_in[2];
  const float* wk = (const float*)d_in[3];
  const float* bk = (const float*)d_in[4];
  const float* wv = (const float*)d_in[5];
  const float* bv = (const float*)d_in[6];
  const float* wf = (const float*)d_in[7];
  const float* bf_ = (const float*)d_in[8];
  float* out = (float*)d_out;

  char* ws = (char*)d_ws;
  bf16* xb  = (bf16*)(ws);                  // 8 MB  [4096 x 1024]
  bf16* wqb = (bf16*)(ws + (8u << 20));     // 2 MB each
  bf16* wkb = (bf16*)(ws + (10u << 20));
  bf16* wvb = (bf16*)(ws + (12u << 20));
  bf16* wfb = (bf16*)(ws + (14u << 20));
  bf16* qd  = (bf16*)(ws + (16u << 20));    // 8 MB [B,H,S,D]
  bf16* kd  = (bf16*)(ws + (24u << 20));    // 8 MB [B,H,S,D]
  bf16* vT  = (bf16*)(ws + (32u << 20));    // 8 MB [B,H,D,S]
  bf16* ao  = (bf16*)(ws + (40u << 20));    // 8 MB [B,S,H*D]

  cvt_bf16<<<4096, 256, 0, stream>>>(x, xb, 1048576);
  cvt_bf16<<<1024, 256, 0, stream>>>(wq, wqb, 262144);
  cvt_bf16<<<1024, 256, 0, stream>>>(wk, wkb, 262144);
  cvt_bf16<<<1024, 256, 0, stream>>>(wv, wvb, 262144);
  cvt_bf16<<<1024, 256, 0, stream>>>(wf, wfb, 262144);

  qkv_gemm<<<dim3(8, 32, 3), 256, 0, stream>>>(xb, wqb, wkb, wvb, bq, bk, bv,
                                               qd, kd, vT);
  attn_kernel<<<dim3(16, 32), 512, 0, stream>>>(qd, kd, vT, ao);
  fc_gemm<<<dim3(8, 32), 256, 0, stream>>>(ao, wfb, bf_, out);
}

// Round 12
// 269.020 us; speedup vs baseline: 1.0191x; 1.0191x over previous
//
#include <hip/hip_runtime.h>
#include <hip/hip_bf16.h>

typedef __hip_bfloat16 bf16;
typedef __attribute__((ext_vector_type(8))) short bf16x8;   // 8 bf16 = 4 VGPRs
typedef __attribute__((ext_vector_type(4))) float f32x4;
typedef __attribute__((ext_vector_type(16))) float f32x16;

static constexpr int SEQ = 2048;   // sequence length
static constexpr int HDIM = 1024;  // H*D
static constexpr int NH = 16;      // heads
static constexpr int DH = 64;      // per-head dim

__device__ __forceinline__ f32x4 mfma16(bf16x8 a, bf16x8 b, f32x4 c) {
  return __builtin_amdgcn_mfma_f32_16x16x32_bf16(a, b, c, 0, 0, 0);
}
__device__ __forceinline__ f32x16 mfma32(bf16x8 a, bf16x8 b, f32x16 c) {
  return __builtin_amdgcn_mfma_f32_32x32x16_bf16(a, b, c, 0, 0, 0);
}

// async global->LDS, 16B per lane
__device__ __forceinline__ void gload_lds16(const bf16* g, bf16* l) {
  __builtin_amdgcn_global_load_lds(
      (const __attribute__((address_space(1))) void*)g,
      (__attribute__((address_space(3))) void*)l, 16, 0, 0);
}

// v_cvt_pk_bf16_f32: two f32 -> one u32 holding 2 bf16 (RNE)
__device__ __forceinline__ unsigned cvtpk(float lo, float hi) {
  unsigned r;
  asm("v_cvt_pk_bf16_f32 %0, %1, %2" : "=v"(r) : "v"(lo), "v"(hi));
  return r;
}
// v_permlane32_swap_b32 a, b (DISTINCT values only — same-value tied operands
// can coalesce to one register and break the swap; see round-8 post-mortem):
//   a'[32:63] = b[0:31]   (lane L>=32 of a' gets b[L-32])
//   b'[0:31]  = a[32:63]  (lane L<32  of b' gets a[L+32])
__device__ __forceinline__ void plswap(unsigned& a, unsigned& b) {
  asm volatile("v_permlane32_swap_b32 %0, %1" : "+v"(a), "+v"(b));
}
// cross-half reduce via shfl (ds_bpermute) — round-2-proven correct
__device__ __forceinline__ float xhalf_max(float x) {
  return fmaxf(x, __shfl_xor(x, 32));
}
__device__ __forceinline__ float xhalf_sum(float x) {
  return x + __shfl_xor(x, 32);
}
__device__ __forceinline__ float max3f(float a, float b, float c) {
  return fmaxf(fmaxf(a, b), c);  // fuses to v_max3_f32
}

// ---------------- fp32 -> bf16 convert (vectorized) ----------------
__global__ __launch_bounds__(256) void cvt_bf16(const float* __restrict__ in,
                                                bf16* __restrict__ out, int n4) {
  int i = blockIdx.x * blockDim.x + threadIdx.x;
  if (i >= n4) return;
  float4 v = reinterpret_cast<const float4*>(in)[i];
  bf16 t[4] = {__float2bfloat16(v.x), __float2bfloat16(v.y),
               __float2bfloat16(v.z), __float2bfloat16(v.w)};
  reinterpret_cast<ushort4*>(out)[i] = *reinterpret_cast<ushort4*>(t);
}

// fused 4-weight convert (one launch instead of four)
__global__ __launch_bounds__(256)
void cvt_w4(const float* __restrict__ w0, const float* __restrict__ w1,
            const float* __restrict__ w2, const float* __restrict__ w3,
            bf16* __restrict__ o0, bf16* __restrict__ o1,
            bf16* __restrict__ o2, bf16* __restrict__ o3) {
  const int z = blockIdx.z;
  const float* in = (z == 0) ? w0 : (z == 1) ? w1 : (z == 2) ? w2 : w3;
  bf16* out = (z == 0) ? o0 : (z == 1) ? o1 : (z == 2) ? o2 : o3;
  int i = blockIdx.x * blockDim.x + threadIdx.x;   // 262144 float4 per weight
  float4 v = reinterpret_cast<const float4*>(in)[i];
  bf16 t[4] = {__float2bfloat16(v.x), __float2bfloat16(v.y),
               __float2bfloat16(v.z), __float2bfloat16(v.w)};
  reinterpret_cast<ushort4*>(out)[i] = *reinterpret_cast<ushort4*>(t);
}

// ---------------- GEMM core: C[128x128] += A[128xK] * W[128xK]^T ----------------
__device__ __forceinline__ void gemm_core(const bf16* __restrict__ A,
                                          const bf16* __restrict__ W,
                                          int m0, int n0, int K,
                                          f32x4 (&acc)[4][4],
                                          bf16* As, bf16* Bs) {
  const int tid = threadIdx.x;
  const int w = tid >> 6, lane = tid & 63;
  const int wr = w >> 1, wc = w & 1;
  const int lr = lane & 15, lk = (lane >> 4) * 8;
  const int srow = lane >> 2, scol = (lane & 3) * 8;

  for (int kt = 0; kt < K; kt += 32) {
#pragma unroll
    for (int j = 0; j < 2; ++j) {
      int cidx = w * 2 + j;
      int r = cidx * 16 + srow;
      gload_lds16(A + (size_t)(m0 + r) * K + kt + scol, As + cidx * 512);
      gload_lds16(W + (size_t)(n0 + r) * K + kt + scol, Bs + cidx * 512);
    }
    __syncthreads();
    bf16x8 af[4], bw[4];
#pragma unroll
    for (int i = 0; i < 4; ++i)
      af[i] = *reinterpret_cast<const bf16x8*>(As + (wr * 64 + i * 16 + lr) * 32 + lk);
#pragma unroll
    for (int i = 0; i < 4; ++i)
      bw[i] = *reinterpret_cast<const bf16x8*>(Bs + (wc * 64 + i * 16 + lr) * 32 + lk);
#pragma unroll
    for (int r = 0; r < 4; ++r)
#pragma unroll
      for (int c = 0; c < 4; ++c)
        acc[r][c] = mfma16(af[r], bw[c], acc[r][c]);
    __syncthreads();
  }
}

// ---------------- fused QKV projection ----------------
// z=0: Q -> [B,H,S,D], pre-scaled by (1/sqrt(D))*log2(e) so softmax is exp2-domain
__global__ __launch_bounds__(256)
void qkv_gemm(const bf16* __restrict__ xb,
              const bf16* __restrict__ wq, const bf16* __restrict__ wk,
              const bf16* __restrict__ wv,
              const float* __restrict__ bq, const float* __restrict__ bk,
              const float* __restrict__ bv,
              bf16* __restrict__ qd, bf16* __restrict__ kd, bf16* __restrict__ vT) {
  __shared__ bf16 As[128 * 32], Bs[128 * 32];
  const int z = blockIdx.z;
  const bf16* W = (z == 0) ? wq : (z == 1) ? wk : wv;
  const float* bias = (z == 0) ? bq : (z == 1) ? bk : bv;
  const float scale = (z == 0) ? 0.18033688011f : 1.0f;  // 0.125 * log2(e)
  const int m0 = blockIdx.y * 128, n0 = blockIdx.x * 128;
  f32x4 acc[4][4] = {};
  gemm_core(xb, W, m0, n0, HDIM, acc, As, Bs);

  const int tid = threadIdx.x, w = tid >> 6, lane = tid & 63;
  const int wr = w >> 1, wc = w & 1;
  const int lr = lane & 15, rg = (lane >> 4) * 4;
#pragma unroll
  for (int r = 0; r < 4; ++r)
#pragma unroll
    for (int c = 0; c < 4; ++c) {
      int n = n0 + wc * 64 + c * 16 + lr;
      int h = n >> 6, d = n & 63;
      float bz = bias[n];
#pragma unroll
      for (int q = 0; q < 4; ++q) {
        int m = m0 + wr * 64 + r * 16 + rg + q;
        int b = m >> 11, s = m & 2047;
        bf16 val = __float2bfloat16((acc[r][c][q] + bz) * scale);
        if (z == 2)
          vT[(((size_t)(b * NH + h) * DH + d) << 11) + s] = val;
        else {
          bf16* dst = (z == 0) ? qd : kd;
          dst[(((size_t)(b * NH + h) * SEQ + s) << 6) + d] = val;
        }
      }
    }
}

// ---------------- flash attention, swapped QK^T + in-block split-K ----------------
// grid (S/128, B*H), 512 threads = 8 waves.
// wave wv: qw = wv&3 selects 32 q-rows; kh = wv>>2 selects k-half (1024 rows).
__global__ __launch_bounds__(512, 4)
void attn_kernel(const bf16* __restrict__ Q, const bf16* __restrict__ K,
                 const bf16* __restrict__ vT, bf16* __restrict__ AO) {
  __shared__ float Olds[4][32][64];           // kh=1 partial O
  __shared__ float mlds[4][32], llds[4][32];  // kh=1 partial m, l
  __shared__ float als[8][32];                // per-wave alpha broadcast
  __shared__ float af1[4][32], af2[4][32], li[4][32];

  const int lane = threadIdx.x & 63;
  const int wv = threadIdx.x >> 6;
  const int qw = wv & 3, kh = wv >> 2;
  const int l31 = lane & 31;
  const int hi = lane >> 5;
  const int bh = blockIdx.y;
  const int b = bh >> 4, h = bh & 15;
  const int q0 = blockIdx.x * 128 + qw * 32;

  const bf16* Qh = Q + (size_t)bh * SEQ * DH;
  const bf16* Kh = K + (size_t)bh * SEQ * DH;
  const bf16* Vh = vT + (size_t)bh * DH * SEQ;

  // Q B-frags hoisted: col=q=l31, k-elems d = step*16 + hi*8 + i
  bf16x8 qf[4];
#pragma unroll
  for (int s = 0; s < 4; ++s)
    qf[s] = *reinterpret_cast<const bf16x8*>(
        Qh + (size_t)(q0 + l31) * DH + s * 16 + hi * 8);

  f32x16 o0 = {}, o1 = {};           // O[q-set][d], d = {0..31, 32..63}
  float m = -1e30f, l = 0.f;         // log2-domain softmax state for q = l31

  const int k_lo = kh << 10;
  // incrementing pointers, constant immediate offsets inside the tile
  const bf16* kptr = Kh + (size_t)(k_lo + l31) * DH + hi * 8;
  const bf16* vp0 = Vh + (size_t)l31 * SEQ + k_lo + hi * 8;
  const bf16* vp1 = Vh + (size_t)(32 + l31) * SEQ + k_lo + hi * 8;

  for (int it = 0; it < 32; ++it) {
    // QK^T swapped: A = K (row=k, contiguous d), B = Q (col=q)
    f32x16 sacc = {};
#pragma unroll
    for (int s = 0; s < 4; ++s) {
      bf16x8 kf = *reinterpret_cast<const bf16x8*>(kptr + s * 16);
      sacc = mfma32(kf, qf[s], sacc);
    }
    kptr += 32 * DH;
    // V B-frags: col=d (within tile), k contiguous from vT[d][k]
    bf16x8 vf[2][2];
#pragma unroll
    for (int kk = 0; kk < 2; ++kk) {
      vf[kk][0] = *reinterpret_cast<const bf16x8*>(vp0 + kk * 16);
      vf[kk][1] = *reinterpret_cast<const bf16x8*>(vp1 + kk * 16);
    }
    vp0 += 32; vp1 += 32;

    // row max: max3 tree + 1 cross-half shfl
    float t0 = max3f(sacc[0], sacc[1], sacc[2]);
    float t1 = max3f(sacc[3], sacc[4], sacc[5]);
    float t2 = max3f(sacc[6], sacc[7], sacc[8]);
    float t3 = max3f(sacc[9], sacc[10], sacc[11]);
    float t4 = max3f(sacc[12], sacc[13], sacc[14]);
    float pmax = fmaxf(max3f(t0, t1, t2), max3f(t3, t4, sacc[15]));
    pmax = xhalf_max(pmax);

    if (__any(pmax > m + 11.5415603f)) {  // defer-max (8 nats in log2 units)
      float mn = fmaxf(m, pmax);
      float al = exp2f(m - mn);           // first tile: exp2(-inf) = 0
      m = mn; l *= al;
      if (lane < 32) als[wv][l31] = al;
      __builtin_amdgcn_wave_barrier();
#pragma unroll
      for (int r = 0; r < 16; ++r) {
        float a = als[wv][(r & 3) + 8 * (r >> 2) + 4 * hi];
        o0[r] *= a; o1[r] *= a;
      }
      __builtin_amdgcn_wave_barrier();
    }

    float p[16];
#pragma unroll
    for (int i = 0; i < 16; ++i) p[i] = exp2f(sacc[i] - m);
    // sum: pairwise tree + 1 cross-half shfl
    float ts[8];
#pragma unroll
    for (int i = 0; i < 8; ++i) ts[i] = p[2 * i] + p[2 * i + 1];
#pragma unroll
    for (int i = 0; i < 4; ++i) ts[i] = ts[i] + ts[i + 4];
    float ps = (ts[0] + ts[1]) + (ts[2] + ts[3]);
    l += xhalf_sum(ps);

    // pack P pairs with cvt_pk; permlane32_swap builds both PV A-frag halves:
    // swap(w[g][j], w[g+1][j]) -> a' = u[j] (own lo / peer hi),
    //                             b' = u[j+2] (peer lo / own hi)
    unsigned u00 = cvtpk(p[0], p[1]),  u01 = cvtpk(p[2], p[3]);    // g=0
    unsigned u10 = cvtpk(p[4], p[5]),  u11 = cvtpk(p[6], p[7]);    // g=1
    unsigned u20 = cvtpk(p[8], p[9]),  u21 = cvtpk(p[10], p[11]);  // g=2
    unsigned u30 = cvtpk(p[12], p[13]), u31 = cvtpk(p[14], p[15]); // g=3
    plswap(u00, u10);  // u00 -> fa0.u[0], u10 -> fa0.u[2]
    plswap(u01, u11);  // u01 -> fa0.u[1], u11 -> fa0.u[3]
    plswap(u20, u30);  // kh tile half 1
    plswap(u21, u31);

    union { unsigned u[4]; bf16x8 v; } fa0, fa1;
    fa0.u[0] = u00; fa0.u[1] = u01; fa0.u[2] = u10; fa0.u[3] = u11;
    fa1.u[0] = u20; fa1.u[1] = u21; fa1.u[2] = u30; fa1.u[3] = u31;
    o0 = mfma32(fa0.v, vf[0][0], o0);
    o1 = mfma32(fa0.v, vf[0][1], o1);
    o0 = mfma32(fa1.v, vf[1][0], o0);
    o1 = mfma32(fa1.v, vf[1][1], o1);
  }

  // ---- merge the two k-halves through LDS ----
  if (kh == 1) {
    if (lane < 32) { mlds[qw][l31] = m; llds[qw][l31] = l; }
#pragma unroll
    for (int r = 0; r < 16; ++r) {
      int q = (r & 3) + 8 * (r >> 2) + 4 * hi;
      Olds[qw][q][l31] = o0[r];
      Olds[qw][q][32 + l31] = o1[r];
    }
  }
  __syncthreads();
  if (kh == 0) {
    float m2 = mlds[qw][l31], l2 = llds[qw][l31];
    float mn = fmaxf(m, m2);
    float a1 = exp2f(m - mn), a2 = exp2f(m2 - mn);
    float inv = 1.0f / (l * a1 + l2 * a2);
    if (lane < 32) { af1[qw][l31] = a1; af2[qw][l31] = a2; li[qw][l31] = inv; }
    __builtin_amdgcn_wave_barrier();
#pragma unroll
    for (int r = 0; r < 16; ++r) {
      int q = (r & 3) + 8 * (r >> 2) + 4 * hi;
      float s1 = af1[qw][q], s2 = af2[qw][q], iv = li[qw][q];
      size_t row = (size_t)(b * SEQ + q0 + q) * HDIM + h * DH;
      AO[row + l31] =
          __float2bfloat16((o0[r] * s1 + Olds[qw][q][l31] * s2) * iv);
      AO[row + 32 + l31] =
          __float2bfloat16((o1[r] * s1 + Olds[qw][q][32 + l31] * s2) * iv);
    }
  }
}

// ---------------- final projection: fp32 out ----------------
__global__ __launch_bounds__(256)
void fc_gemm(const bf16* __restrict__ A, const bf16* __restrict__ W,
             const float* __restrict__ bias, float* __restrict__ out) {
  __shared__ bf16 As[128 * 32], Bs[128 * 32];
  const int m0 = blockIdx.y * 128, n0 = blockIdx.x * 128;
  f32x4 acc[4][4] = {};
  gemm_core(A, W, m0, n0, HDIM, acc, As, Bs);

  const int tid = threadIdx.x, w = tid >> 6, lane = tid & 63;
  const int wr = w >> 1, wc = w & 1;
  const int lr = lane & 15, rg = (lane >> 4) * 4;
#pragma unroll
  for (int r = 0; r < 4; ++r)
#pragma unroll
    for (int c = 0; c < 4; ++c) {
      int n = n0 + wc * 64 + c * 16 + lr;
      float bz = bias[n];
#pragma unroll
      for (int q = 0; q < 4; ++q) {
        int m = m0 + wr * 64 + r * 16 + rg + q;
        out[(size_t)m * HDIM + n] = acc[r][c][q] + bz;
      }
    }
}

extern "C" void kernel_launch(void* const* d_in, const int* in_sizes, int n_in,
                              void* d_out, int out_size, void* d_ws, size_t ws_size,
                              hipStream_t stream) {
  (void)in_sizes; (void)n_in; (void)out_size; (void)ws_size;
  const float* x  = (const float*)d_in[0];
  const float* wq = (const float*)d_in[1];
  const float* bq = (const float*)d_in[2];
  const float* wk = (const float*)d_in[3];
  const float* bk = (const float*)d_in[4];
  const float* wv = (const float*)d_in[5];
  const float* bv = (const float*)d_in[6];
  const float* wf = (const float*)d_in[7];
  const float* bf_ = (const float*)d_in[8];
  float* out = (float*)d_out;

  char* ws = (char*)d_ws;
  bf16* xb  = (bf16*)(ws);                  // 8 MB  [4096 x 1024]
  bf16* wqb = (bf16*)(ws + (8u << 20));     // 2 MB each
  bf16* wkb = (bf16*)(ws + (10u << 20));
  bf16* wvb = (bf16*)(ws + (12u << 20));
  bf16* wfb = (bf16*)(ws + (14u << 20));
  bf16* qd  = (bf16*)(ws + (16u << 20));    // 8 MB [B,H,S,D]
  bf16* kd  = (bf16*)(ws + (24u << 20));    // 8 MB [B,H,S,D]
  bf16* vT  = (bf16*)(ws + (32u << 20));    // 8 MB [B,H,D,S]
  bf16* ao  = (bf16*)(ws + (40u << 20));    // 8 MB [B,S,H*D]

  cvt_bf16<<<4096, 256, 0, stream>>>(x, xb, 1048576);
  cvt_w4<<<dim3(1024, 1, 4), 256, 0, stream>>>(wq, wk, wv, wf,
                                               wqb, wkb, wvb, wfb);

  qkv_gemm<<<dim3(8, 32, 3), 256, 0, stream>>>(xb, wqb, wkb, wvb, bq, bk, bv,
                                               qd, kd, vT);
  attn_kernel<<<dim3(16, 32), 512, 0, stream>>>(qd, kd, vT, ao);
  fc_gemm<<<dim3(8, 32), 256, 0, stream>>>(ao, wfb, bf_, out);
}